// Round 2
// baseline (800.222 us; speedup 1.0000x reference)
//
#include <hip/hip_runtime.h>

constexpr int NNODES = 100000;
constexpr int NEDGES = 1280000;
constexpr int SCAN_ELEMS = 1024;                       // elems per scan block
constexpr int NSCAN = (NNODES + SCAN_ELEMS - 1) / SCAN_ELEMS;  // 98

// ---------------------------------------------------------------------------
// Edge kernel: block of 256 threads handles 64 edges.
// SCATTER=true: legacy atomic path (fallback only).
// SCATTER=false: pure streaming edge_out = edge_feat @ rel_w.
// ---------------------------------------------------------------------------
template <bool SCATTER>
__global__ __launch_bounds__(256) void edge_fused_kernel(
    const float* __restrict__ edge_feat,
    const float* __restrict__ node_feat,
    const float* __restrict__ edge_norm,
    const int*   __restrict__ src,
    const int*   __restrict__ dst,
    const int*   __restrict__ is_rev,
    const float* __restrict__ rel_w,
    float* __restrict__ accF,
    float* __restrict__ accR,
    float* __restrict__ edge_out)
{
    __shared__ float Xs[64][64];
    const int tid   = threadIdx.x;
    const int lane  = tid & 63;
    const int wv    = tid >> 6;
    const int ebase = blockIdx.x * 64;

    float w[64];
#pragma unroll
    for (int k = 0; k < 64; ++k) w[k] = rel_w[k * 64 + lane];

#pragma unroll
    for (int i = 0; i < 16; ++i) {
        const int r = wv * 16 + i;
        const int e = ebase + r;
        const float ef = edge_feat[(size_t)e * 64 + lane];
        Xs[r][lane] = ef;
        if (SCATTER) {
            const int   s  = src[e];
            const int   d  = dst[e];
            const int   rv = is_rev[e];
            const float nm = edge_norm[e];
            const float comp = ef * node_feat[(size_t)s * 64 + lane];
            float* accp = rv ? accR : accF;
            unsafeAtomicAdd(accp + (size_t)d * 64 + lane, comp * nm);
        }
    }
    __syncthreads();

#pragma unroll 1
    for (int i = 0; i < 16; ++i) {
        const int r = wv * 16 + i;
        const float4* xr = (const float4*)(&Xs[r][0]);
        float a0 = 0.f, a1 = 0.f, a2 = 0.f, a3 = 0.f;
#pragma unroll
        for (int k4 = 0; k4 < 16; ++k4) {
            const float4 x = xr[k4];
            a0 += x.x * w[k4 * 4 + 0];
            a1 += x.y * w[k4 * 4 + 1];
            a2 += x.z * w[k4 * 4 + 2];
            a3 += x.w * w[k4 * 4 + 3];
        }
        edge_out[(size_t)(ebase + r) * 64 + lane] = (a0 + a1) + (a2 + a3);
    }
}

// ---------------------------------------------------------------------------
// CSR build
// ---------------------------------------------------------------------------
__global__ __launch_bounds__(256) void k_count(const int* __restrict__ dst,
                                               int* __restrict__ cnt)
{
    const int e = blockIdx.x * 256 + threadIdx.x;
    if (e < NEDGES) atomicAdd(&cnt[dst[e]], 1);
}

// Per-block exclusive scan of 1024 elems (256 thr x 4), emits block totals.
__global__ __launch_bounds__(256) void k_scan1(const int* __restrict__ cnt,
                                               int* __restrict__ excl,
                                               int* __restrict__ partials)
{
    __shared__ int s[256];
    const int base = blockIdx.x * SCAN_ELEMS + threadIdx.x * 4;
    int v0 = 0, v1 = 0, v2 = 0, v3 = 0;
    if (base + 0 < NNODES) v0 = cnt[base + 0];
    if (base + 1 < NNODES) v1 = cnt[base + 1];
    if (base + 2 < NNODES) v2 = cnt[base + 2];
    if (base + 3 < NNODES) v3 = cnt[base + 3];
    const int tsum = v0 + v1 + v2 + v3;
    s[threadIdx.x] = tsum;
    __syncthreads();
    for (int off = 1; off < 256; off <<= 1) {
        const int t = (threadIdx.x >= off) ? s[threadIdx.x - off] : 0;
        __syncthreads();
        s[threadIdx.x] += t;
        __syncthreads();
    }
    const int texcl = s[threadIdx.x] - tsum;
    if (base + 0 < NNODES) excl[base + 0] = texcl;
    if (base + 1 < NNODES) excl[base + 1] = texcl + v0;
    if (base + 2 < NNODES) excl[base + 2] = texcl + v0 + v1;
    if (base + 3 < NNODES) excl[base + 3] = texcl + v0 + v1 + v2;
    if (threadIdx.x == 255) partials[blockIdx.x] = s[255];
}

// Exclusive scan of NSCAN (<=128) block totals, in place.
__global__ __launch_bounds__(128) void k_scan2(int* __restrict__ partials, int n)
{
    __shared__ int s[128];
    const int v = (threadIdx.x < n) ? partials[threadIdx.x] : 0;
    s[threadIdx.x] = v;
    __syncthreads();
    for (int off = 1; off < 128; off <<= 1) {
        const int t = (threadIdx.x >= off) ? s[threadIdx.x - off] : 0;
        __syncthreads();
        s[threadIdx.x] += t;
        __syncthreads();
    }
    if (threadIdx.x < n) partials[threadIdx.x] = s[threadIdx.x] - v;
}

__global__ __launch_bounds__(256) void k_addback(const int* __restrict__ excl,
                                                 const int* __restrict__ partials,
                                                 int* __restrict__ rowptr,
                                                 int* __restrict__ cursor)
{
    const int i = blockIdx.x * 256 + threadIdx.x;
    if (i < NNODES) {
        const int v = excl[i] + partials[i >> 10];
        rowptr[i] = v;
        cursor[i] = v;
    }
    if (i == 0) rowptr[NNODES] = NEDGES;
}

// Scatter packed per-edge metadata into CSR order: {edge, src, norm, is_rev}.
__global__ __launch_bounds__(256) void k_scatter(const int* __restrict__ dst,
                                                 const int* __restrict__ src,
                                                 const float* __restrict__ norm,
                                                 const int* __restrict__ is_rev,
                                                 int* __restrict__ cursor,
                                                 int4* __restrict__ meta)
{
    const int e = blockIdx.x * 256 + threadIdx.x;
    if (e >= NEDGES) return;
    const int d = dst[e];
    const int pos = atomicAdd(&cursor[d], 1);
    meta[pos] = make_int4(e, src[e], __float_as_int(norm[e]), is_rev[e]);
}

// ---------------------------------------------------------------------------
// Aggregation: one wave per node (grid-stride). No atomics: each node row
// accumulated in registers, written once.
// ---------------------------------------------------------------------------
__global__ __launch_bounds__(256) void k_agg(
    const float* __restrict__ edge_feat,
    const float* __restrict__ node_feat,
    const int*   __restrict__ rowptr,
    const int4*  __restrict__ meta,
    float* __restrict__ accF,
    float* __restrict__ accR)
{
    const int lane   = threadIdx.x & 63;
    const int wid    = (blockIdx.x * blockDim.x + threadIdx.x) >> 6;
    const int nwaves = (gridDim.x * blockDim.x) >> 6;

    for (int n = wid; n < NNODES; n += nwaves) {
        const int start = rowptr[n];
        const int end   = rowptr[n + 1];
        float af = 0.f, ar = 0.f;
        int j = start;
        for (; j + 1 < end; j += 2) {
            const int4 m0 = meta[j];
            const int4 m1 = meta[j + 1];
            const float ef0 = edge_feat[(size_t)m0.x * 64 + lane];
            const float nf0 = node_feat[(size_t)m0.y * 64 + lane];
            const float ef1 = edge_feat[(size_t)m1.x * 64 + lane];
            const float nf1 = node_feat[(size_t)m1.y * 64 + lane];
            const float v0 = ef0 * nf0 * __int_as_float(m0.z);
            const float v1 = ef1 * nf1 * __int_as_float(m1.z);
            af += m0.w ? 0.f : v0;
            ar += m0.w ? v0 : 0.f;
            af += m1.w ? 0.f : v1;
            ar += m1.w ? v1 : 0.f;
        }
        if (j < end) {
            const int4 m0 = meta[j];
            const float v0 = edge_feat[(size_t)m0.x * 64 + lane] *
                             node_feat[(size_t)m0.y * 64 + lane] *
                             __int_as_float(m0.z);
            af += m0.w ? 0.f : v0;
            ar += m0.w ? v0 : 0.f;
        }
        accF[(size_t)n * 64 + lane] = af;
        accR[(size_t)n * 64 + lane] = ar;
    }
}

// ---------------------------------------------------------------------------
// Node kernel (unchanged; in-place safe for accF == node_out).
// ---------------------------------------------------------------------------
__global__ __launch_bounds__(256) void node_kernel(
    const float* __restrict__ accF,
    const float* __restrict__ accR,
    const float* __restrict__ node_feat,
    const float* __restrict__ in_w,
    const float* __restrict__ out_w,
    const float* __restrict__ loop_w,
    const float* __restrict__ loop_rel,
    const float* __restrict__ bias,
    float* __restrict__ node_out)
{
    __shared__ float XF[64][64];
    __shared__ float XR[64][64];
    __shared__ float XN[64][64];
    const int tid   = threadIdx.x;
    const int lane  = tid & 63;
    const int wv    = tid >> 6;
    const int nbase = blockIdx.x * 64;

    float wi[64], wo[64], wl[64];
#pragma unroll
    for (int k = 0; k < 64; ++k) {
        wi[k] = in_w[k * 64 + lane];
        wo[k] = out_w[k * 64 + lane];
        wl[k] = loop_w[k * 64 + lane] * loop_rel[k];
    }
    const float b = bias[lane];

#pragma unroll
    for (int i = 0; i < 16; ++i) {
        const int r = wv * 16 + i;
        const int n = nbase + r;
        if (n < NNODES) {
            XF[r][lane] = accF[(size_t)n * 64 + lane];
            XR[r][lane] = accR[(size_t)n * 64 + lane];
            XN[r][lane] = node_feat[(size_t)n * 64 + lane];
        }
    }
    __syncthreads();

#pragma unroll 1
    for (int i = 0; i < 16; ++i) {
        const int r = wv * 16 + i;
        const int n = nbase + r;
        if (n >= NNODES) continue;
        const float4* xf = (const float4*)(&XF[r][0]);
        const float4* xg = (const float4*)(&XR[r][0]);
        const float4* xh = (const float4*)(&XN[r][0]);
        float a0 = 0.f, a1 = 0.f, a2 = 0.f, a3 = 0.f;
#pragma unroll
        for (int k4 = 0; k4 < 16; ++k4) {
            const float4 f = xf[k4];
            const float4 g = xg[k4];
            const float4 h = xh[k4];
            a0 += f.x * wi[k4 * 4 + 0] + g.x * wo[k4 * 4 + 0] + h.x * wl[k4 * 4 + 0];
            a1 += f.y * wi[k4 * 4 + 1] + g.y * wo[k4 * 4 + 1] + h.y * wl[k4 * 4 + 1];
            a2 += f.z * wi[k4 * 4 + 2] + g.z * wo[k4 * 4 + 2] + h.z * wl[k4 * 4 + 2];
            a3 += f.w * wi[k4 * 4 + 3] + g.w * wo[k4 * 4 + 3] + h.w * wl[k4 * 4 + 3];
        }
        node_out[(size_t)n * 64 + lane] =
            ((a0 + a1) + (a2 + a3)) * 0.3333333f + b;
    }
}

// ---------------------------------------------------------------------------
// Fallback scatter (only if ws too small; known-good path).
// ---------------------------------------------------------------------------
__global__ __launch_bounds__(256) void edge_scatter_kernel(
    const float* __restrict__ edge_feat,
    const float* __restrict__ node_feat,
    const float* __restrict__ edge_norm,
    const int*   __restrict__ src,
    const int*   __restrict__ dst,
    const int*   __restrict__ is_rev,
    float* __restrict__ accF,
    float* __restrict__ accR)
{
    const size_t t = (size_t)blockIdx.x * blockDim.x + threadIdx.x;
    if (t >= (size_t)NEDGES * 64) return;
    const int e    = (int)(t >> 6);
    const int lane = (int)(t & 63);
    const float ef   = edge_feat[(size_t)e * 64 + lane];
    const float comp = ef * node_feat[(size_t)src[e] * 64 + lane];
    float* accp = is_rev[e] ? accR : accF;
    unsafeAtomicAdd(accp + (size_t)dst[e] * 64 + lane, comp * edge_norm[e]);
}

// ---------------------------------------------------------------------------
extern "C" void kernel_launch(void* const* d_in, const int* in_sizes, int n_in,
                              void* d_out, int out_size, void* d_ws, size_t ws_size,
                              hipStream_t stream)
{
    const float* node_feat = (const float*)d_in[0];
    const float* edge_feat = (const float*)d_in[1];
    const float* edge_norm = (const float*)d_in[2];
    const int*   src       = (const int*)d_in[3];
    const int*   dst       = (const int*)d_in[4];
    const int*   is_rev    = (const int*)d_in[5];
    const float* in_w      = (const float*)d_in[6];
    const float* out_w     = (const float*)d_in[7];
    const float* rel_w     = (const float*)d_in[8];
    const float* loop_w    = (const float*)d_in[9];
    const float* loop_rel  = (const float*)d_in[10];
    const float* bias      = (const float*)d_in[11];

    float* node_out = (float*)d_out;
    float* edge_out = (float*)d_out + (size_t)NNODES * 64;

    const size_t accBytes = (size_t)NNODES * 64 * sizeof(float);
    const int nodeBlocks  = (NNODES + 63) / 64;
    const int edgeBlocks  = NEDGES / 64;
    const int edgeThreadBlocks = (NEDGES + 255) / 256;

    // ws layout
    char* p = (char*)d_ws;
    int* cnt      = (int*)p;                 p += (size_t)NNODES * 4;
    int* excl     = (int*)p;                 p += (size_t)NNODES * 4;
    int* partials = (int*)p;                 p += 128 * 4;
    int* rowptr   = (int*)p;                 p += (size_t)(NNODES + 1) * 4;
    int* cursor   = (int*)p;                 p += (size_t)NNODES * 4;
    p = (char*)(((uintptr_t)p + 15) & ~(uintptr_t)15);
    int4* meta    = (int4*)p;                p += (size_t)NEDGES * 16;
    const size_t needed = (size_t)(p - (char*)d_ws);

    // accF borrows node_out (node_kernel is in-place safe);
    // accR borrows edge_out (overwritten afterwards by the edge GEMM).
    float* accF = node_out;
    float* accR = edge_out;

    if (ws_size >= needed) {
        hipMemsetAsync(cnt, 0, (size_t)NNODES * 4, stream);
        hipMemsetAsync(d_out, 0, 2 * accBytes, stream);   // zero accF + accR

        k_count<<<edgeThreadBlocks, 256, 0, stream>>>(dst, cnt);
        k_scan1<<<NSCAN, 256, 0, stream>>>(cnt, excl, partials);
        k_scan2<<<1, 128, 0, stream>>>(partials, NSCAN);
        k_addback<<<(NNODES + 255) / 256, 256, 0, stream>>>(excl, partials, rowptr, cursor);
        k_scatter<<<edgeThreadBlocks, 256, 0, stream>>>(dst, src, edge_norm, is_rev, cursor, meta);
        k_agg<<<1024, 256, 0, stream>>>(edge_feat, node_feat, rowptr, meta, accF, accR);
        node_kernel<<<nodeBlocks, 256, 0, stream>>>(
            accF, accR, node_feat, in_w, out_w, loop_w, loop_rel, bias, node_out);
        edge_fused_kernel<false><<<edgeBlocks, 256, 0, stream>>>(
            edge_feat, node_feat, edge_norm, src, dst, is_rev, rel_w,
            nullptr, nullptr, edge_out);
    } else {
        // Fallback: legacy atomic path with d_out borrowing.
        hipMemsetAsync(d_out, 0, 2 * accBytes, stream);
        edge_scatter_kernel<<<(int)(((size_t)NEDGES * 64 + 255) / 256), 256, 0, stream>>>(
            edge_feat, node_feat, edge_norm, src, dst, is_rev, accF, accR);
        node_kernel<<<nodeBlocks, 256, 0, stream>>>(
            accF, accR, node_feat, in_w, out_w, loop_w, loop_rel, bias, node_out);
        edge_fused_kernel<false><<<edgeBlocks, 256, 0, stream>>>(
            edge_feat, node_feat, edge_norm, src, dst, is_rev, rel_w,
            nullptr, nullptr, edge_out);
    }
}

// Round 3
// 685.397 us; speedup vs baseline: 1.1675x; 1.1675x over previous
//
#include <hip/hip_runtime.h>

constexpr int NNODES = 100000;
constexpr int NEDGES = 1280000;
constexpr int SCAN_ELEMS = 1024;
constexpr int NSCAN = (NNODES + SCAN_ELEMS - 1) / SCAN_ELEMS;  // 98

// ---------------------------------------------------------------------------
// Edge GEMM: C[E,64] = X[E,64] @ W[64,64].
// Block tile 128 rows x 64 cols; thread tile 8 rows x 4 cols.
// W staged in LDS (per-lane-distinct b128 reads, 2-way alias = free);
// A read directly from global (wave-uniform rows -> coalesced L1 broadcast).
// ---------------------------------------------------------------------------
__global__ __launch_bounds__(256) void edge_gemm(
    const float* __restrict__ X,
    const float* __restrict__ W,
    float* __restrict__ C)
{
    __shared__ float Ws[64][64];
    const int tid = threadIdx.x;
    {
        const float4* Wv = (const float4*)W;
        float4* Sv = (float4*)&Ws[0][0];
#pragma unroll
        for (int j = 0; j < 4; ++j) Sv[tid + 256 * j] = Wv[tid + 256 * j];
    }
    __syncthreads();

    const int tx = tid & 15;     // cols 4*tx..4*tx+3
    const int ty = tid >> 4;     // rows rbase..rbase+7
    const size_t rbase = (size_t)blockIdx.x * 128 + 8 * ty;
    const float* Xp = X + rbase * 64;

    float acc[8][4] = {};
#pragma unroll 2
    for (int kc = 0; kc < 16; ++kc) {
        float4 b[4];
#pragma unroll
        for (int kk = 0; kk < 4; ++kk)
            b[kk] = *(const float4*)&Ws[4 * kc + kk][4 * tx];
#pragma unroll
        for (int i = 0; i < 8; ++i) {
            const float4 a = ((const float4*)(Xp + (size_t)i * 64))[kc];
            acc[i][0] += a.x * b[0].x + a.y * b[1].x + a.z * b[2].x + a.w * b[3].x;
            acc[i][1] += a.x * b[0].y + a.y * b[1].y + a.z * b[2].y + a.w * b[3].y;
            acc[i][2] += a.x * b[0].z + a.y * b[1].z + a.z * b[2].z + a.w * b[3].z;
            acc[i][3] += a.x * b[0].w + a.y * b[1].w + a.z * b[2].w + a.w * b[3].w;
        }
    }
#pragma unroll
    for (int i = 0; i < 8; ++i) {
        float4 o = make_float4(acc[i][0], acc[i][1], acc[i][2], acc[i][3]);
        *(float4*)(C + (rbase + (size_t)i) * 64 + 4 * tx) = o;
    }
}

// ---------------------------------------------------------------------------
// Node GEMM: node_out = (accF@Wi + accR@Wo + nf@diag(lr)Wl)/3 + bias.
// Same tiling, K=192 over 3 sources. Reads complete -> barrier -> stores,
// so accF==node_out / accR==edge_out borrowing is race-free.
// ---------------------------------------------------------------------------
__global__ __launch_bounds__(256) void node_gemm(
    const float* __restrict__ XF,
    const float* __restrict__ XR,
    const float* __restrict__ XN,
    const float* __restrict__ Wi,
    const float* __restrict__ Wo,
    const float* __restrict__ Wl,
    const float* __restrict__ loop_rel,
    const float* __restrict__ bias,
    float* __restrict__ C)
{
    __shared__ float Ws[192][64];
    const int tid = threadIdx.x;
    {
        const float4* wv;
        float4* sv = (float4*)&Ws[0][0];
        wv = (const float4*)Wi;
#pragma unroll
        for (int j = 0; j < 4; ++j) sv[tid + 256 * j] = wv[tid + 256 * j];
        wv = (const float4*)Wo;
#pragma unroll
        for (int j = 0; j < 4; ++j) sv[1024 + tid + 256 * j] = wv[tid + 256 * j];
        wv = (const float4*)Wl;
#pragma unroll
        for (int j = 0; j < 4; ++j) {
            const int f = tid + 256 * j;        // float4 index; row k = f/16
            float4 v = wv[f];
            const float s = loop_rel[f >> 4];
            v.x *= s; v.y *= s; v.z *= s; v.w *= s;
            sv[2048 + f] = v;
        }
    }
    __syncthreads();

    const int tx = tid & 15;
    const int ty = tid >> 4;
    const size_t rbase = (size_t)blockIdx.x * 128 + 8 * ty;

    float acc[8][4] = {};
    const float* srcs[3] = { XF, XR, XN };
#pragma unroll
    for (int s = 0; s < 3; ++s) {
        const float* Xs = srcs[s];
#pragma unroll 2
        for (int kc = 0; kc < 16; ++kc) {
            float4 b[4];
#pragma unroll
            for (int kk = 0; kk < 4; ++kk)
                b[kk] = *(const float4*)&Ws[s * 64 + 4 * kc + kk][4 * tx];
#pragma unroll
            for (int i = 0; i < 8; ++i) {
                size_t r = rbase + (size_t)i;
                if (r >= NNODES) r = NNODES - 1;   // clamped (discarded at store)
                const float4 a = ((const float4*)(Xs + r * 64))[kc];
                acc[i][0] += a.x * b[0].x + a.y * b[1].x + a.z * b[2].x + a.w * b[3].x;
                acc[i][1] += a.x * b[0].y + a.y * b[1].y + a.z * b[2].y + a.w * b[3].y;
                acc[i][2] += a.x * b[0].z + a.y * b[1].z + a.z * b[2].z + a.w * b[3].z;
                acc[i][3] += a.x * b[0].w + a.y * b[1].w + a.z * b[2].w + a.w * b[3].w;
            }
        }
    }
    const float4 bb = *(const float4*)(bias + 4 * tx);
    __syncthreads();   // all reads done before any in-place store
#pragma unroll
    for (int i = 0; i < 8; ++i) {
        const size_t r = rbase + (size_t)i;
        if (r < NNODES) {
            float4 o;
            o.x = acc[i][0] * 0.3333333f + bb.x;
            o.y = acc[i][1] * 0.3333333f + bb.y;
            o.z = acc[i][2] * 0.3333333f + bb.z;
            o.w = acc[i][3] * 0.3333333f + bb.w;
            *(float4*)(C + r * 64 + 4 * tx) = o;
        }
    }
}

// ---------------------------------------------------------------------------
// CSR build
// ---------------------------------------------------------------------------
__global__ __launch_bounds__(256) void k_count(const int* __restrict__ dst,
                                               int* __restrict__ cnt)
{
    const int e = blockIdx.x * 256 + threadIdx.x;
    if (e < NEDGES) atomicAdd(&cnt[dst[e]], 1);
}

__global__ __launch_bounds__(256) void k_scan1(const int* __restrict__ cnt,
                                               int* __restrict__ excl,
                                               int* __restrict__ partials)
{
    __shared__ int s[256];
    const int base = blockIdx.x * SCAN_ELEMS + threadIdx.x * 4;
    int v0 = 0, v1 = 0, v2 = 0, v3 = 0;
    if (base + 0 < NNODES) v0 = cnt[base + 0];
    if (base + 1 < NNODES) v1 = cnt[base + 1];
    if (base + 2 < NNODES) v2 = cnt[base + 2];
    if (base + 3 < NNODES) v3 = cnt[base + 3];
    const int tsum = v0 + v1 + v2 + v3;
    s[threadIdx.x] = tsum;
    __syncthreads();
    for (int off = 1; off < 256; off <<= 1) {
        const int t = (threadIdx.x >= off) ? s[threadIdx.x - off] : 0;
        __syncthreads();
        s[threadIdx.x] += t;
        __syncthreads();
    }
    const int texcl = s[threadIdx.x] - tsum;
    if (base + 0 < NNODES) excl[base + 0] = texcl;
    if (base + 1 < NNODES) excl[base + 1] = texcl + v0;
    if (base + 2 < NNODES) excl[base + 2] = texcl + v0 + v1;
    if (base + 3 < NNODES) excl[base + 3] = texcl + v0 + v1 + v2;
    if (threadIdx.x == 255) partials[blockIdx.x] = s[255];
}

__global__ __launch_bounds__(128) void k_scan2(int* __restrict__ partials, int n)
{
    __shared__ int s[128];
    const int v = (threadIdx.x < n) ? partials[threadIdx.x] : 0;
    s[threadIdx.x] = v;
    __syncthreads();
    for (int off = 1; off < 128; off <<= 1) {
        const int t = (threadIdx.x >= off) ? s[threadIdx.x - off] : 0;
        __syncthreads();
        s[threadIdx.x] += t;
        __syncthreads();
    }
    if (threadIdx.x < n) partials[threadIdx.x] = s[threadIdx.x] - v;
}

__global__ __launch_bounds__(256) void k_addback(const int* __restrict__ excl,
                                                 const int* __restrict__ partials,
                                                 int* __restrict__ rowptr,
                                                 int* __restrict__ cursor)
{
    const int i = blockIdx.x * 256 + threadIdx.x;
    if (i < NNODES) {
        const int v = excl[i] + partials[i >> 10];
        rowptr[i] = v;
        cursor[i] = v;
    }
    if (i == 0) rowptr[NNODES] = NEDGES;
}

__global__ __launch_bounds__(256) void k_scatter(const int* __restrict__ dst,
                                                 const int* __restrict__ src,
                                                 const float* __restrict__ norm,
                                                 const int* __restrict__ is_rev,
                                                 int* __restrict__ cursor,
                                                 int4* __restrict__ meta)
{
    const int e = blockIdx.x * 256 + threadIdx.x;
    if (e >= NEDGES) return;
    const int d = dst[e];
    const int pos = atomicAdd(&cursor[d], 1);
    meta[pos] = make_int4(e, src[e], __float_as_int(norm[e]), is_rev[e]);
}

// ---------------------------------------------------------------------------
// Aggregation: ONE WAVE PER NODE (100K waves), unroll-4 gather, no atomics.
// ---------------------------------------------------------------------------
__global__ __launch_bounds__(256) void k_agg(
    const float* __restrict__ edge_feat,
    const float* __restrict__ node_feat,
    const int*   __restrict__ rowptr,
    const int4*  __restrict__ meta,
    float* __restrict__ accF,
    float* __restrict__ accR)
{
    const int lane = threadIdx.x & 63;
    const int n    = (blockIdx.x * blockDim.x + threadIdx.x) >> 6;
    if (n >= NNODES) return;

    const int start = rowptr[n];
    const int end   = rowptr[n + 1];
    float af = 0.f, ar = 0.f;
    int j = start;
    for (; j + 3 < end; j += 4) {
        const int4 m0 = meta[j], m1 = meta[j + 1], m2 = meta[j + 2], m3 = meta[j + 3];
        const float e0 = edge_feat[(size_t)m0.x * 64 + lane];
        const float f0 = node_feat[(size_t)m0.y * 64 + lane];
        const float e1 = edge_feat[(size_t)m1.x * 64 + lane];
        const float f1 = node_feat[(size_t)m1.y * 64 + lane];
        const float e2 = edge_feat[(size_t)m2.x * 64 + lane];
        const float f2 = node_feat[(size_t)m2.y * 64 + lane];
        const float e3 = edge_feat[(size_t)m3.x * 64 + lane];
        const float f3 = node_feat[(size_t)m3.y * 64 + lane];
        const float v0 = e0 * f0 * __int_as_float(m0.z);
        const float v1 = e1 * f1 * __int_as_float(m1.z);
        const float v2 = e2 * f2 * __int_as_float(m2.z);
        const float v3 = e3 * f3 * __int_as_float(m3.z);
        af += m0.w ? 0.f : v0;  ar += m0.w ? v0 : 0.f;
        af += m1.w ? 0.f : v1;  ar += m1.w ? v1 : 0.f;
        af += m2.w ? 0.f : v2;  ar += m2.w ? v2 : 0.f;
        af += m3.w ? 0.f : v3;  ar += m3.w ? v3 : 0.f;
    }
    for (; j < end; ++j) {
        const int4 m0 = meta[j];
        const float v0 = edge_feat[(size_t)m0.x * 64 + lane] *
                         node_feat[(size_t)m0.y * 64 + lane] *
                         __int_as_float(m0.z);
        af += m0.w ? 0.f : v0;
        ar += m0.w ? v0 : 0.f;
    }
    accF[(size_t)n * 64 + lane] = af;
    accR[(size_t)n * 64 + lane] = ar;
}

// ---------------------------------------------------------------------------
// Fallback scatter (only if ws too small).
// ---------------------------------------------------------------------------
__global__ __launch_bounds__(256) void edge_scatter_kernel(
    const float* __restrict__ edge_feat,
    const float* __restrict__ node_feat,
    const float* __restrict__ edge_norm,
    const int*   __restrict__ src,
    const int*   __restrict__ dst,
    const int*   __restrict__ is_rev,
    float* __restrict__ accF,
    float* __restrict__ accR)
{
    const size_t t = (size_t)blockIdx.x * blockDim.x + threadIdx.x;
    if (t >= (size_t)NEDGES * 64) return;
    const int e    = (int)(t >> 6);
    const int lane = (int)(t & 63);
    const float ef   = edge_feat[(size_t)e * 64 + lane];
    const float comp = ef * node_feat[(size_t)src[e] * 64 + lane];
    float* accp = is_rev[e] ? accR : accF;
    unsafeAtomicAdd(accp + (size_t)dst[e] * 64 + lane, comp * edge_norm[e]);
}

// ---------------------------------------------------------------------------
extern "C" void kernel_launch(void* const* d_in, const int* in_sizes, int n_in,
                              void* d_out, int out_size, void* d_ws, size_t ws_size,
                              hipStream_t stream)
{
    const float* node_feat = (const float*)d_in[0];
    const float* edge_feat = (const float*)d_in[1];
    const float* edge_norm = (const float*)d_in[2];
    const int*   src       = (const int*)d_in[3];
    const int*   dst       = (const int*)d_in[4];
    const int*   is_rev    = (const int*)d_in[5];
    const float* in_w      = (const float*)d_in[6];
    const float* out_w     = (const float*)d_in[7];
    const float* rel_w     = (const float*)d_in[8];
    const float* loop_w    = (const float*)d_in[9];
    const float* loop_rel  = (const float*)d_in[10];
    const float* bias      = (const float*)d_in[11];

    float* node_out = (float*)d_out;
    float* edge_out = (float*)d_out + (size_t)NNODES * 64;

    const size_t accBytes = (size_t)NNODES * 64 * sizeof(float);
    const int edgeThreadBlocks = (NEDGES + 255) / 256;
    const int edgeGemmBlocks   = NEDGES / 128;               // 10000
    const int nodeGemmBlocks   = (NNODES + 127) / 128;       // 782
    const int aggBlocks        = (NNODES + 3) / 4;           // 25000

    // ws layout
    char* p = (char*)d_ws;
    int* cnt      = (int*)p;                 p += (size_t)NNODES * 4;
    int* excl     = (int*)p;                 p += (size_t)NNODES * 4;
    int* partials = (int*)p;                 p += 128 * 4;
    int* rowptr   = (int*)p;                 p += (size_t)(NNODES + 1) * 4;
    int* cursor   = (int*)p;                 p += (size_t)NNODES * 4;
    p = (char*)(((uintptr_t)p + 15) & ~(uintptr_t)15);
    int4* meta    = (int4*)p;                p += (size_t)NEDGES * 16;
    const size_t needed = (size_t)(p - (char*)d_ws);

    // accF borrows node_out (node_gemm in-place safe via pre-store barrier);
    // accR borrows edge_out (overwritten afterwards by edge_gemm).
    float* accF = node_out;
    float* accR = edge_out;

    if (ws_size >= needed) {
        hipMemsetAsync(cnt, 0, (size_t)NNODES * 4, stream);
        k_count<<<edgeThreadBlocks, 256, 0, stream>>>(dst, cnt);
        k_scan1<<<NSCAN, 256, 0, stream>>>(cnt, excl, partials);
        k_scan2<<<1, 128, 0, stream>>>(partials, NSCAN);
        k_addback<<<(NNODES + 255) / 256, 256, 0, stream>>>(excl, partials, rowptr, cursor);
        k_scatter<<<edgeThreadBlocks, 256, 0, stream>>>(dst, src, edge_norm, is_rev, cursor, meta);
        k_agg<<<aggBlocks, 256, 0, stream>>>(edge_feat, node_feat, rowptr, meta, accF, accR);
        node_gemm<<<nodeGemmBlocks, 256, 0, stream>>>(
            accF, accR, node_feat, in_w, out_w, loop_w, loop_rel, bias, node_out);
        edge_gemm<<<edgeGemmBlocks, 256, 0, stream>>>(edge_feat, rel_w, edge_out);
    } else {
        hipMemsetAsync(d_out, 0, 2 * accBytes, stream);
        edge_scatter_kernel<<<(int)(((size_t)NEDGES * 64 + 255) / 256), 256, 0, stream>>>(
            edge_feat, node_feat, edge_norm, src, dst, is_rev, accF, accR);
        node_gemm<<<nodeGemmBlocks, 256, 0, stream>>>(
            accF, accR, node_feat, in_w, out_w, loop_w, loop_rel, bias, node_out);
        edge_gemm<<<edgeGemmBlocks, 256, 0, stream>>>(edge_feat, rel_w, edge_out);
    }
}